// Round 4
// baseline (883.101 us; speedup 1.0000x reference)
//
#include <hip/hip_runtime.h>
#include <math.h>
#include <stdint.h>

#define S_LEN 2048
#define DMODEL 1024
#define NH 8
#define DK_ 128
#define DV_ 128
#define KD_ 1024
#define KCONV 4
#define WSTEPS 16

typedef short bf16x8 __attribute__((ext_vector_type(8)));
typedef float f32x4 __attribute__((ext_vector_type(4)));

__device__ __forceinline__ uint16_t f2bf(float f) {  // RNE
  uint32_t u = __float_as_uint(f);
  u += 0x7FFF + ((u >> 16) & 1);
  return (uint16_t)(u >> 16);
}

__device__ __forceinline__ void glds16(const uint16_t* g, uint16_t* l) {
  __builtin_amdgcn_global_load_lds(
      (const __attribute__((address_space(1))) void*)g,
      (__attribute__((address_space(3))) void*)l, 16, 0, 0);
}

__device__ __forceinline__ float dot4(float4 a, float4 b) {
  return fmaf(a.w, b.w, fmaf(a.z, b.z, fmaf(a.y, b.y, a.x * b.x)));
}

// ---------------- fused fp32 -> bf16 cast for up to 8 tensors ----------------
struct CastArgs {
  const float* s[8];
  uint16_t* d[8];
  int n[8];
};
__global__ __launch_bounds__(256) void cast_multi(CastArgs a) {
  int i = blockIdx.y;
  int base = (blockIdx.x * 256 + threadIdx.x) * 8;
  if (base >= a.n[i]) return;
  const float4* sp = (const float4*)(a.s[i] + base);
  float4 x0 = sp[0], x1 = sp[1];
  uint32_t p0 = (uint32_t)f2bf(x0.x) | ((uint32_t)f2bf(x0.y) << 16);
  uint32_t p1 = (uint32_t)f2bf(x0.z) | ((uint32_t)f2bf(x0.w) << 16);
  uint32_t p2 = (uint32_t)f2bf(x1.x) | ((uint32_t)f2bf(x1.y) << 16);
  uint32_t p3 = (uint32_t)f2bf(x1.z) | ((uint32_t)f2bf(x1.w) << 16);
  uint4 v = {p0, p1, p2, p3};
  *(uint4*)(a.d[i] + base) = v;
}

// ---------------- bf16 MFMA GEMM: C[M,N] = A[M,K] @ B[N,K]^T ----------------
// 128x128 tile, BK=32, 4 waves, 16x16x32 MFMA, global_load_lds, XOR swizzle.
// Batched jobs with per-job N and output dtype.
struct GJobs {
  const uint16_t* A[5];
  const uint16_t* B[5];
  void* C[5];
  int N[5];
  int outbf[5];
};
__global__ __launch_bounds__(256) void gemm_mfma(GJobs j, int K) {
  const int z = blockIdx.z;
  const int N = j.N[z];
  const int n0 = blockIdx.x * 128;
  if (n0 >= N) return;
  __shared__ uint16_t Asb[128 * 32];
  __shared__ uint16_t Bsb[128 * 32];
  const uint16_t* __restrict__ A = j.A[z];
  const uint16_t* __restrict__ B = j.B[z];
  const int tid = threadIdx.x;
  const int w = tid >> 6, lane = tid & 63;
  const int m0 = blockIdx.y * 128;
  const int mw = (w & 1) * 64, nw = (w >> 1) * 64;
  const int c0 = tid, c1 = 256 + tid;
  const int r0 = c0 >> 2, cl0 = (c0 & 3) ^ ((r0 >> 2) & 3);
  const int r1 = c1 >> 2, cl1 = (c1 & 3) ^ ((r1 >> 2) & 3);
  const uint16_t* gA0 = A + (size_t)(m0 + r0) * K + cl0 * 8;
  const uint16_t* gA1 = A + (size_t)(m0 + r1) * K + cl1 * 8;
  const uint16_t* gB0 = B + (size_t)(n0 + r0) * K + cl0 * 8;
  const uint16_t* gB1 = B + (size_t)(n0 + r1) * K + cl1 * 8;
  uint16_t* lA0 = Asb + w * 512;
  uint16_t* lA1 = Asb + 2048 + w * 512;
  uint16_t* lB0 = Bsb + w * 512;
  uint16_t* lB1 = Bsb + 2048 + w * 512;

  const int l15 = lane & 15, q = lane >> 4;
  const int ccq = q ^ ((l15 >> 2) & 3);

  f32x4 acc[4][4] = {};
  for (int k0 = 0; k0 < K; k0 += 32) {
    glds16(gA0 + k0, lA0);
    glds16(gA1 + k0, lA1);
    glds16(gB0 + k0, lB0);
    glds16(gB1 + k0, lB1);
    __syncthreads();
    bf16x8 af[4], bfr[4];
#pragma unroll
    for (int i = 0; i < 4; i++)
      af[i] = *(const bf16x8*)&Asb[(mw + i * 16 + l15) * 32 + ccq * 8];
#pragma unroll
    for (int jx = 0; jx < 4; jx++)
      bfr[jx] = *(const bf16x8*)&Bsb[(nw + jx * 16 + l15) * 32 + ccq * 8];
#pragma unroll
    for (int i = 0; i < 4; i++)
#pragma unroll
      for (int jx = 0; jx < 4; jx++)
        acc[i][jx] = __builtin_amdgcn_mfma_f32_16x16x32_bf16(af[i], bfr[jx],
                                                             acc[i][jx], 0, 0, 0);
    __syncthreads();
  }
  const int obf = j.outbf[z];
#pragma unroll
  for (int i = 0; i < 4; i++) {
#pragma unroll
    for (int jx = 0; jx < 4; jx++) {
      int n = n0 + nw + jx * 16 + l15;
#pragma unroll
      for (int r = 0; r < 4; r++) {
        int m = m0 + mw + i * 16 + q * 4 + r;
        if (obf)
          ((uint16_t*)j.C[z])[(size_t)m * N + n] = f2bf(acc[i][jx][r]);
        else
          ((float*)j.C[z])[(size_t)m * N + n] = acc[i][jx][r];
      }
    }
  }
}

// ---------------- fp32 GEMM (numerically-sensitive g-path + Wb) -----
__global__ __launch_bounds__(256) void gemm_abt(
    const float* __restrict__ A, const float* __restrict__ B,
    float* __restrict__ C, int M, int N, int Kd) {
  __shared__ float As[16][68];
  __shared__ float Bs[16][68];
  const int tid = threadIdx.x;
  const int m0 = blockIdx.y * 64, n0 = blockIdx.x * 64;
  const int tx = tid & 15, ty = tid >> 4;
  const int lk = tid & 15, lr = tid >> 4;
  float acc[4][4] = {};
  for (int k0 = 0; k0 < Kd; k0 += 16) {
#pragma unroll
    for (int i = 0; i < 4; i++) {
      int m = m0 + lr + 16 * i;
      As[lk][lr + 16 * i] = (m < M) ? A[(size_t)m * Kd + k0 + lk] : 0.f;
      int n = n0 + lr + 16 * i;
      Bs[lk][lr + 16 * i] = (n < N) ? B[(size_t)n * Kd + k0 + lk] : 0.f;
    }
    __syncthreads();
#pragma unroll
    for (int kk = 0; kk < 16; kk++) {
      float4 a4 = *(const float4*)&As[kk][ty * 4];
      float4 b4 = *(const float4*)&Bs[kk][tx * 4];
      float av[4] = {a4.x, a4.y, a4.z, a4.w};
      float bv[4] = {b4.x, b4.y, b4.z, b4.w};
#pragma unroll
      for (int i = 0; i < 4; i++)
#pragma unroll
        for (int jx = 0; jx < 4; jx++) acc[i][jx] = fmaf(av[i], bv[jx], acc[i][jx]);
    }
    __syncthreads();
  }
#pragma unroll
  for (int i = 0; i < 4; i++) {
    int m = m0 + ty * 4 + i;
    if (m >= M) continue;
#pragma unroll
    for (int jx = 0; jx < 4; jx++) {
      int n = n0 + tx * 4 + jx;
      if (n < N) C[(size_t)m * N + n] = acc[i][jx];
    }
  }
}

// -------- depthwise causal conv(K=4) + silu for q,k,v and ve; mix v ----------
__global__ __launch_bounds__(256) void conv_silu_mix(
    const float* __restrict__ qp, const float* __restrict__ kp,
    const float* __restrict__ vp, const float* __restrict__ vep,
    const float* __restrict__ wq, const float* __restrict__ wk,
    const float* __restrict__ wv, const float* __restrict__ lam,
    float* __restrict__ qc, float* __restrict__ kc, float* __restrict__ vmx) {
  int idx = blockIdx.x * 256 + threadIdx.x;
  if (idx >= S_LEN * KD_) return;
  int s = idx >> 10, d = idx & 1023;
  float aq = 0.f, ak = 0.f, av = 0.f, ae = 0.f;
#pragma unroll
  for (int i = 0; i < KCONV; i++) {
    int ss = s - (KCONV - 1) + i;
    if (ss < 0) continue;
    size_t off = (size_t)ss * KD_ + d;
    aq = fmaf(qp[off], wq[d * KCONV + i], aq);
    ak = fmaf(kp[off], wk[d * KCONV + i], ak);
    av = fmaf(vp[off], wv[d * KCONV + i], av);
    ae = fmaf(vep[off], wv[d * KCONV + i], ae);
  }
  qc[idx] = aq / (1.f + expf(-aq));
  kc[idx] = ak / (1.f + expf(-ak));
  float sv = av / (1.f + expf(-av));
  float se = ae / (1.f + expf(-ae));
  vmx[idx] = lam[0] * sv + lam[1] * se;
}

// ------ eg = exp(-exp(A_log)*softplus(graw+dt_bias)) in place ------
__global__ __launch_bounds__(256) void eg_only(
    float* __restrict__ graw, const float* __restrict__ dt_bias,
    const float* __restrict__ A_log) {
  int idx = blockIdx.x * 256 + threadIdx.x;
  if (idx >= S_LEN * KD_) return;
  int c = idx & 1023;
  float xv = graw[idx] + dt_bias[c];
  float sp = (xv > 20.f) ? xv : log1pf(expf(xv));
  graw[idx] = expf(-expf(A_log[c >> 7]) * sp);
}

// ---- DPP 16-lane-row butterflies (2-way and 3-way interleaved) ----
#define DPPADD(x, ctrl) \
  x += __int_as_float(__builtin_amdgcn_update_dpp(0, __float_as_int(x), ctrl, 0xF, 0xF, true))

__device__ __forceinline__ void row16_sum2(float& a, float& b) {
  DPPADD(a, 0xB1); DPPADD(b, 0xB1);
  DPPADD(a, 0x4E); DPPADD(b, 0x4E);
  DPPADD(a, 0x141); DPPADD(b, 0x141);
  DPPADD(a, 0x140); DPPADD(b, 0x140);
}
__device__ __forceinline__ void row16_sum3(float& a, float& b, float& c) {
  DPPADD(a, 0xB1); DPPADD(b, 0xB1); DPPADD(c, 0xB1);
  DPPADD(a, 0x4E); DPPADD(b, 0x4E); DPPADD(c, 0x4E);
  DPPADD(a, 0x141); DPPADD(b, 0x141); DPPADD(c, 0x141);
  DPPADD(a, 0x140); DPPADD(b, 0x140); DPPADD(c, 0x140);
}

// ---------------- KDA recurrent scan ----------------
// block=(h,vg): 16 v-cols. wave lane = kg(16) x vsub(4); col = wave*4+vsub.
// LDS layout per stream/window: two 1024-float halves; elem e of step s at
// half=(e>>2)&1, offset (s*16 + (e>>3))*4 + (e&3)  -> staging writes are
// lane-contiguous float4 (conflict-free), reads are 2-way (free).
// l2norm of q,k fused into staging; beta sigmoid fused into staging.
// qd = q.t + vnw*(q.k) decomposition removes 2nd reduction from serial path.
__global__ __launch_bounds__(256) void kda_scan(
    const float* __restrict__ qc, const float* __restrict__ kc,
    const float* __restrict__ vm, const float* __restrict__ eg,
    const float* __restrict__ bpre, float* __restrict__ o) {
  __shared__ float kbuf[2][2048];
  __shared__ float qbuf[2][2048];
  __shared__ float ebuf[2][2048];
  __shared__ float vbuf[2][WSTEPS * 16];
  __shared__ float bbuf[2][WSTEPS];
  const int h = blockIdx.x >> 3;
  const int vg = blockIdx.x & 7;
  const int tid = threadIdx.x;
  const int kg = tid & 15;
  const int colw = (tid >> 6) * 4 + ((tid >> 4) & 3);

  float4 rk0, rk1, rq0, rq1, re0, re1;
  float rv, rb;

  auto load_regs = [&](int w0) {
    size_t row = (size_t)w0 * WSTEPS + (tid >> 4);
    size_t off = row * KD_ + h * DK_ + (tid & 15) * 8;
    rk0 = *(const float4*)(kc + off); rk1 = *(const float4*)(kc + off + 4);
    rq0 = *(const float4*)(qc + off); rq1 = *(const float4*)(qc + off + 4);
    re0 = *(const float4*)(eg + off); re1 = *(const float4*)(eg + off + 4);
    rv = vm[row * KD_ + h * DV_ + vg * 16 + (tid & 15)];
    rb = (tid < WSTEPS)
             ? bpre[((size_t)w0 * WSTEPS + tid) * NH + h]
             : 0.f;
  };
  auto commit = [&](int b) {
    // fused l2norm over the 16 fkg lanes of this row (= this step)
    float sk = dot4(rk0, rk0) + dot4(rk1, rk1);
    float sq = dot4(rq0, rq0) + dot4(rq1, rq1);
    row16_sum2(sk, sq);
    float rkn = rsqrtf(sk + 1e-6f);
    float rqn = rsqrtf(sq + 1e-6f) * 0.08838834764831845f;  // * DK^-0.5
    rk0.x *= rkn; rk0.y *= rkn; rk0.z *= rkn; rk0.w *= rkn;
    rk1.x *= rkn; rk1.y *= rkn; rk1.z *= rkn; rk1.w *= rkn;
    rq0.x *= rqn; rq0.y *= rqn; rq0.z *= rqn; rq0.w *= rqn;
    rq1.x *= rqn; rq1.y *= rqn; rq1.z *= rqn; rq1.w *= rqn;
    *(float4*)&kbuf[b][tid * 4] = rk0;
    *(float4*)&kbuf[b][1024 + tid * 4] = rk1;
    *(float4*)&qbuf[b][tid * 4] = rq0;
    *(float4*)&qbuf[b][1024 + tid * 4] = rq1;
    *(float4*)&ebuf[b][tid * 4] = re0;
    *(float4*)&ebuf[b][1024 + tid * 4] = re1;
    vbuf[b][tid] = rv;
    if (tid < WSTEPS) bbuf[b][tid] = 1.f / (1.f + expf(-rb));
  };

  load_regs(0);
  commit(0);
  __syncthreads();

  float S0 = 0, S1 = 0, S2 = 0, S3 = 0, S4 = 0, S5 = 0, S6 = 0, S7 = 0;
  float4 kA = *(float4*)&kbuf[0][kg * 4], kB = *(float4*)&kbuf[0][1024 + kg * 4];
  float4 qA = *(float4*)&qbuf[0][kg * 4], qB = *(float4*)&qbuf[0][1024 + kg * 4];
  float4 eA = *(float4*)&ebuf[0][kg * 4], eB = *(float4*)&ebuf[0][1024 + kg * 4];
  float vt = vbuf[0][colw];
  float bt = bbuf[0][0];

  const int NW = S_LEN / WSTEPS;  // 128
  for (int w = 0; w < NW; w++) {
    const int cur = w & 1, nxt = cur ^ 1;
    const bool more = (w + 1 < NW);
    if (more) load_regs(w + 1);  // global loads in flight during compute
#pragma unroll
    for (int s = 0; s < WSTEPS; s++) {
      float4 nkA, nkB, nqA, nqB, neA, neB;
      float nvt = 0.f, nbt = 0.f;
      if (s + 1 < WSTEPS) {  // LDS prefetch of next step
        int idx = ((s + 1) * 16 + kg) * 4;
        nkA = *(float4*)&kbuf[cur][idx]; nkB = *(float4*)&kbuf[cur][1024 + idx];
        nqA = *(float4*)&qbuf[cur][idx]; nqB = *(float4*)&qbuf[cur][1024 + idx];
        neA = *(float4*)&ebuf[cur][idx]; neB = *(float4*)&ebuf[cur][1024 + idx];
        nvt = vbuf[cur][(s + 1) * 16 + colw];
        nbt = bbuf[cur][s + 1];
      }
      // t = e * S (decayed state, pre-update)
      float4 tA, tB;
      tA.x = eA.x * S0; tA.y = eA.y * S1; tA.z = eA.z * S2; tA.w = eA.w * S3;
      tB.x = eB.x * S4; tB.y = eB.y * S5; tB.z = eB.z * S6; tB.w = eB.w * S7;
      // three independent dots; reductions interleaved
      float kd = dot4(kA, tA) + dot4(kB, tB);
      float qt = dot4(qA, tA) + dot4(qB, tB);
      float qk = dot4(qA, kA) + dot4(qB, kB);
      row16_sum3(kd, qt, qk);
      float vnw = (vt - kd) * bt;
      // state update (off the qd critical path)
      S0 = fmaf(kA.x, vnw, tA.x); S1 = fmaf(kA.y, vnw, tA.y);
      S2 = fmaf(kA.z, vnw, tA.z); S3 = fmaf(kA.w, vnw, tA.w);
      S4 = fmaf(kB.x, vnw, tB.x); S5 = fmaf(kB.y, vnw, tB.y);
      S6 = fmaf(kB.z, vnw, tB.z); S7 = fmaf(kB.w, vnw, tB.w);
      float qd = fmaf(vnw, qk, qt);
      if (kg == 0)
        o[(size_t)(w * WSTEPS + s) * KD_ + h * DK_ + vg * 16 + colw] = qd;
      if (s + 1 < WSTEPS) {
        kA = nkA; kB = nkB; qA = nqA; qB = nqB; eA = neA; eB = neB;
        vt = nvt; bt = nbt;
      }
    }
    if (more) commit(nxt);
    __syncthreads();
    if (more) {
      kA = *(float4*)&kbuf[nxt][kg * 4]; kB = *(float4*)&kbuf[nxt][1024 + kg * 4];
      qA = *(float4*)&qbuf[nxt][kg * 4]; qB = *(float4*)&qbuf[nxt][1024 + kg * 4];
      eA = *(float4*)&ebuf[nxt][kg * 4]; eB = *(float4*)&ebuf[nxt][1024 + kg * 4];
      vt = vbuf[nxt][colw];
      bt = bbuf[nxt][0];
    }
  }
}

// ---- FusedRMSNormGated: gate = sigmoid(g2raw + bg2) fused; bf16 out ----
__global__ __launch_bounds__(64) void gated_rmsnorm(
    const float* __restrict__ o, const float* __restrict__ g2raw,
    const float* __restrict__ bg2, const float* __restrict__ wn,
    uint16_t* __restrict__ ob) {
  size_t base = (size_t)blockIdx.x * DV_;
  int t = threadIdx.x;
  float a = o[base + t], b = o[base + t + 64];
  float ss = a * a + b * b;
#pragma unroll
  for (int off = 32; off > 0; off >>= 1) ss += __shfl_xor(ss, off);
  float r = rsqrtf(ss * (1.f / 128.f) + 1e-5f);
  int c0 = (int)((base + t) & 1023), c1 = (int)((base + t + 64) & 1023);
  float ga = 1.f / (1.f + expf(-(g2raw[base + t] + bg2[c0])));
  float gb = 1.f / (1.f + expf(-(g2raw[base + t + 64] + bg2[c1])));
  ob[base + t] = f2bf(a * r * wn[t] * ga);
  ob[base + t + 64] = f2bf(b * r * wn[t + 64] * gb);
}

extern "C" void kernel_launch(void* const* d_in, const int* in_sizes, int n_in,
                              void* d_out, int out_size, void* d_ws, size_t ws_size,
                              hipStream_t stream) {
  const float* x = (const float*)d_in[0];
  const float* ve = (const float*)d_in[1];
  const float* lam = (const float*)d_in[2];
  const float* Wq = (const float*)d_in[3];
  const float* Wk = (const float*)d_in[4];
  const float* Wv = (const float*)d_in[5];
  const float* Wo = (const float*)d_in[6];
  const float* wq_conv = (const float*)d_in[7];
  const float* wk_conv = (const float*)d_in[8];
  const float* wv_conv = (const float*)d_in[9];
  const float* Wf1 = (const float*)d_in[10];
  const float* Wf2 = (const float*)d_in[11];
  const float* Wb = (const float*)d_in[12];
  const float* A_log = (const float*)d_in[13];
  const float* dt_bias = (const float*)d_in[14];
  const float* Wg1 = (const float*)d_in[15];
  const float* Wg2 = (const float*)d_in[16];
  const float* bg2 = (const float*)d_in[17];
  const float* w_norm = (const float*)d_in[18];
  float* out = (float*)d_out;

  float* ws = (float*)d_ws;
  const size_t SZ = (size_t)S_LEN * KD_;  // 2M
  float* q_pre = ws;
  float* k_pre = ws + SZ;
  float* v_pre = ws + 2 * SZ;
  float* ve_pre = ws + 3 * SZ;
  float* q_c = ws + 4 * SZ;
  float* k_c = ws + 5 * SZ;
  float* v_mix = ws + 6 * SZ;
  float* f1 = ve_pre;                              // [S,128] after conv
  float* bpre = ve_pre + 2 * (size_t)S_LEN * DV_;  // [S,8] raw (sigmoid in scan)
  float* graw = q_pre;                             // -> eg in place
  float* g2raw = k_pre;                            // raw gate pre-activation
  float* o_buf = v_pre;
  uint16_t* bws = (uint16_t*)(ws + 7 * SZ);
  uint16_t* xb = bws;
  uint16_t* veb = xb + SZ;
  uint16_t* Wqb = veb + SZ;
  uint16_t* Wkb = Wqb + (size_t)KD_ * DMODEL;
  uint16_t* Wvb = Wkb + (size_t)KD_ * DMODEL;
  uint16_t* Wob = Wvb + (size_t)KD_ * DMODEL;
  uint16_t* Wg1b = Wob + (size_t)DMODEL * KD_;
  uint16_t* Wg2b = Wg1b + (size_t)DV_ * DMODEL;
  uint16_t* g1b = Wg2b + (size_t)KD_ * DV_;        // [S,128] bf16
  uint16_t* ob = g1b + (size_t)S_LEN * DV_;        // [S,1024] bf16

  dim3 blk(256);
  int ew_blocks = (S_LEN * KD_ + 255) / 256;

  CastArgs ca;
  ca.s[0] = x;   ca.d[0] = xb;   ca.n[0] = S_LEN * DMODEL;
  ca.s[1] = ve;  ca.d[1] = veb;  ca.n[1] = S_LEN * DMODEL;
  ca.s[2] = Wq;  ca.d[2] = Wqb;  ca.n[2] = KD_ * DMODEL;
  ca.s[3] = Wk;  ca.d[3] = Wkb;  ca.n[3] = KD_ * DMODEL;
  ca.s[4] = Wv;  ca.d[4] = Wvb;  ca.n[4] = KD_ * DMODEL;
  ca.s[5] = Wo;  ca.d[5] = Wob;  ca.n[5] = DMODEL * KD_;
  ca.s[6] = Wg1; ca.d[6] = Wg1b; ca.n[6] = DV_ * DMODEL;
  ca.s[7] = Wg2; ca.d[7] = Wg2b; ca.n[7] = KD_ * DV_;
  cast_multi<<<dim3(1024, 8), blk, 0, stream>>>(ca);

  // q/k/v/ve projections + g1 (Wg1), one batched launch
  GJobs jq;
  jq.A[0] = xb;  jq.B[0] = Wqb;  jq.C[0] = q_pre;  jq.N[0] = KD_; jq.outbf[0] = 0;
  jq.A[1] = xb;  jq.B[1] = Wkb;  jq.C[1] = k_pre;  jq.N[1] = KD_; jq.outbf[1] = 0;
  jq.A[2] = xb;  jq.B[2] = Wvb;  jq.C[2] = v_pre;  jq.N[2] = KD_; jq.outbf[2] = 0;
  jq.A[3] = veb; jq.B[3] = Wvb;  jq.C[3] = ve_pre; jq.N[3] = KD_; jq.outbf[3] = 0;
  jq.A[4] = xb;  jq.B[4] = Wg1b; jq.C[4] = g1b;    jq.N[4] = DV_; jq.outbf[4] = 1;
  gemm_mfma<<<dim3(8, 16, 5), blk, 0, stream>>>(jq, DMODEL);

  conv_silu_mix<<<ew_blocks, blk, 0, stream>>>(q_pre, k_pre, v_pre, ve_pre,
                                               wq_conv, wk_conv, wv_conv, lam,
                                               q_c, k_c, v_mix);

  // g-decay path fp32
  gemm_abt<<<dim3(2, 32), blk, 0, stream>>>(x, Wf1, f1, S_LEN, DV_, DMODEL);
  gemm_abt<<<dim3(1, 32), blk, 0, stream>>>(x, Wb, bpre, S_LEN, NH, DMODEL);
  gemm_abt<<<dim3(16, 32), blk, 0, stream>>>(f1, Wf2, graw, S_LEN, KD_, DV_);
  eg_only<<<ew_blocks, blk, 0, stream>>>(graw, dt_bias, A_log);

  kda_scan<<<dim3(64), blk, 0, stream>>>(q_c, k_c, v_mix, graw, bpre, o_buf);

  // gate path (independent of scan output) after scan
  GJobs jg2;
  jg2.A[0] = g1b; jg2.B[0] = Wg2b; jg2.C[0] = g2raw; jg2.N[0] = KD_; jg2.outbf[0] = 0;
  gemm_mfma<<<dim3(8, 16, 1), blk, 0, stream>>>(jg2, DV_);

  gated_rmsnorm<<<dim3(S_LEN * NH), dim3(64), 0, stream>>>(o_buf, g2raw, bg2,
                                                           w_norm, ob);

  GJobs jo;
  jo.A[0] = ob; jo.B[0] = Wob; jo.C[0] = out; jo.N[0] = DMODEL; jo.outbf[0] = 0;
  gemm_mfma<<<dim3(8, 16, 1), blk, 0, stream>>>(jo, KD_);
}